// Round 4
// baseline (66.446 us; speedup 1.0000x reference)
//
#include <hip/hip_runtime.h>
#include <math.h>

#define N_MAX 8192
#define N_USERS 1024
#define D 64
#define FB_BLOCKS  128   // fallback blocks FIRST (long pole starts at t=0)
#define REG_BLOCKS 512   // 1024 thr = 16 waves -> 16 rows/block

// Persistent device scratch (rewritten deterministically every launch).
__device__ int   g_mask_int;            // 1 if mask buffer is int32, 0 if bytes
__device__ int   g_off[N_USERS + 1];    // exclusive prefix offsets per user
__device__ int   g_list[N_MAX];         // negative column idx, bucketed by user
__device__ int   g_nfb;                 // # fallback rows
__device__ int   g_fb[N_MAX];           // fallback row ids (order-irrelevant)
__device__ float g_row[N_MAX];          // per-row loss (0 for unmasked rows)

__device__ __forceinline__ bool mask_at(const void* m, int k, bool as_int) {
    return as_int ? (((const int*)m)[k] != 0)
                  : (((const unsigned char*)m)[k] != 0);
}

// ---------------------------------------------------------------------------
// Kernel 1: detect mask dtype; bucket negative columns by user id (LDS
// count + shfl-scan + scatter); emit masked rows with empty buckets.
// Single block of 1024 threads (16 waves).
// ---------------------------------------------------------------------------
__global__ __launch_bounds__(N_USERS) void build_buckets(
    const void* __restrict__ maskp,
    const int* __restrict__ uid, int N)
{
    const int t    = threadIdx.x;
    const int lane = t & 63;
    const int w    = t >> 6;
    __shared__ int cntA[N_USERS];   // per-user negative count (preserved)
    __shared__ int cur[N_USERS];    // scatter cursors
    __shared__ int wsum[16];
    __shared__ int s_or;

    if (t == 0) { s_or = 0; g_nfb = 0; }
    cntA[t] = 0;
    __syncthreads();

    // --- mask dtype detection: int32 0/1 has zero bytes at k%4!=0 ----------
    {
        const unsigned char* mb = (const unsigned char*)maskp;
        int z = 0;
        for (int k = t; k < N; k += N_USERS)
            if (k & 3) z |= mb[k];
        if (z) atomicOr(&s_or, 1);
    }
    __syncthreads();
    const bool as_int = (s_or == 0);
    if (t == 0) g_mask_int = as_int ? 1 : 0;

    // --- count negatives per user (LDS atomics) ----------------------------
    for (int k = t; k < N; k += N_USERS)
        if (!mask_at(maskp, k, as_int)) atomicAdd(&cntA[uid[k]], 1);
    __syncthreads();

    // --- exclusive scan over 1024 counts: wave shfl-scan + wave-sum scan ---
    const int own = cntA[t];
    int inc = own;
    #pragma unroll
    for (int off = 1; off < 64; off <<= 1) {
        int u = __shfl_up(inc, off, 64);
        if (lane >= off) inc += u;
    }
    if (lane == 63) wsum[w] = inc;
    __syncthreads();
    if (w == 0) {
        int s = (lane < 16) ? wsum[lane] : 0;
        #pragma unroll
        for (int off = 1; off < 16; off <<= 1) {
            int u = __shfl_up(s, off, 64);
            if (lane >= off) s += u;
        }
        if (lane < 16) wsum[lane] = s;
    }
    __syncthreads();
    const int base = (w > 0) ? wsum[w - 1] : 0;
    const int excl = base + inc - own;
    g_off[t] = excl;
    if (t == N_USERS - 1) g_off[N_USERS] = base + inc;
    cur[t] = excl;
    __syncthreads();

    // --- scatter negatives into buckets ------------------------------------
    for (int k = t; k < N; k += N_USERS)
        if (!mask_at(maskp, k, as_int)) {
            int p = atomicAdd(&cur[uid[k]], 1);
            g_list[p] = k;
        }

    // --- fallback rows: masked && own user's bucket empty ------------------
    for (int i = t; i < N; i += N_USERS)
        if (mask_at(maskp, i, as_int) && cntA[uid[i]] == 0) {
            int p = atomicAdd(&g_nfb, 1);
            g_fb[p] = i;
        }
}

// ---------------------------------------------------------------------------
// Kernel 2 (fused). Coalesced dot mapping everywhere: 16 lanes per negative
// row k; lane sub holds float4 #sub of the row (contiguous 256 B per k ->
// the 4-cache-line floor per row, no TA fragmentation). Partial dot = 4 FMA,
// reduced with 4x shfl_xor(width 16).
//   blocks [0, FB_BLOCKS): one 1024-thread block per fallback row.
//   blocks [FB_BLOCKS, +REG_BLOCKS): one wave per regular row.
// ---------------------------------------------------------------------------
__global__ __launch_bounds__(1024) void row_kernel(
    const float* __restrict__ inp, const float* __restrict__ tgt,
    const float* __restrict__ q,   const int* __restrict__ tids,
    const int* __restrict__ uid,   const void* __restrict__ maskp,
    int N)
{
    const int t    = threadIdx.x;
    const int lane = t & 63;
    const int w    = t >> 6;
    const int bid  = blockIdx.x;
    const bool as_int = (g_mask_int != 0);

    if (bid >= FB_BLOCKS) {
        // ---------------- regular rows: one wave each ----------------------
        const int i = (bid - FB_BLOCKS) * 16 + w;
        if (i >= N) return;
        if (!mask_at(maskp, i, as_int)) { if (lane == 0) g_row[i] = 0.0f; return; }

        const int u = uid[i];
        const int start = g_off[u], end = g_off[u + 1];
        if (end == start) return;            // fallback block owns this row

        const float a = inp[i * D + lane];
        float p = a * tgt[i * D + lane];
        #pragma unroll
        for (int o = 32; o > 0; o >>= 1) p += __shfl_xor(p, o, 64);

        const int sub = lane & 15;           // float4 slot within a row
        const int kg  = lane >> 4;           // 4 k-groups per wave
        float4 a4;
        a4.x = __shfl(a, (sub << 2) + 0, 64);
        a4.y = __shfl(a, (sub << 2) + 1, 64);
        a4.z = __shfl(a, (sub << 2) + 2, 64);
        a4.w = __shfl(a, (sub << 2) + 3, 64);

        const int my_tid = tids[i];
        float s = 0.0f;
        int   n = 0;
        for (int j = start + kg; j < end; j += 4) {
            const int k = g_list[j];                       // broadcast in group
            const float4 t4 = *(const float4*)(tgt + k * D + (sub << 2));
            float dot = a4.x * t4.x + a4.y * t4.y + a4.z * t4.z + a4.w * t4.w;
            #pragma unroll
            for (int o = 8; o > 0; o >>= 1) dot += __shfl_xor(dot, o, 16);
            if (sub == 0 && tids[k] != my_tid) { s += expf(dot) / q[k]; n++; }
        }
        #pragma unroll
        for (int o = 32; o > 0; o >>= 1) {
            s += __shfl_xor(s, o, 64);
            n += __shfl_xor(n, o, 64);
        }
        if (lane == 0) {
            const float qi      = q[i];
            const float neg_sum = (1.0f - qi) * s / fmaxf((float)n, 1.0f);
            g_row[i] = log1pf(neg_sum * expf(-p));
        }
    } else {
        // ---------------- fallback rows: one block each --------------------
        __shared__ __align__(16) float in_fb[D];
        __shared__ float sfs[16];
        __shared__ int   sfn[16];

        const int nfb  = g_nfb;
        const int ntot = g_off[N_USERS];
        const int sub  = t & 15;
        const int kg   = t >> 4;             // 64 k-groups per block
        for (int r = bid; r < nfb; r += FB_BLOCKS) {
            const int i = g_fb[r];
            if (t < D) in_fb[t] = inp[i * D + t];
            __syncthreads();

            float pos = 0.0f;
            if (w == 0) {                    // wave 0 computes pos_sim
                pos = in_fb[lane] * tgt[i * D + lane];
                #pragma unroll
                for (int o = 32; o > 0; o >>= 1) pos += __shfl_xor(pos, o, 64);
            }
            const float4 a4 = ((const float4*)in_fb)[sub];
            const int my_tid = tids[i];
            float s = 0.0f;
            int   n = 0;
            for (int j = kg; j < ntot; j += 64) {
                const int k = g_list[j];                   // broadcast in group
                const float4 t4 = *(const float4*)(tgt + k * D + (sub << 2));
                float dot = a4.x * t4.x + a4.y * t4.y + a4.z * t4.z + a4.w * t4.w;
                #pragma unroll
                for (int o = 8; o > 0; o >>= 1) dot += __shfl_xor(dot, o, 16);
                if (sub == 0 && tids[k] != my_tid) { s += expf(dot) / q[k]; n++; }
            }
            #pragma unroll
            for (int o = 32; o > 0; o >>= 1) {
                s += __shfl_xor(s, o, 64);
                n += __shfl_xor(n, o, 64);
            }
            if (lane == 0) { sfs[w] = s; sfn[w] = n; }
            __syncthreads();
            if (t == 0) {
                float S = 0.0f; int Nn = 0;
                #pragma unroll
                for (int x = 0; x < 16; ++x) { S += sfs[x]; Nn += sfn[x]; }
                const float qi      = q[i];
                const float neg_sum = (1.0f - qi) * S / fmaxf((float)Nn, 1.0f);
                g_row[i] = log1pf(neg_sum * expf(-pos));
            }
            __syncthreads();                 // protect LDS reuse next r
        }
    }
}

// ---------------------------------------------------------------------------
// Kernel 3: deterministic fixed-order reduction -> scalar loss.
// ---------------------------------------------------------------------------
__global__ __launch_bounds__(1024) void finalize(
    const void* __restrict__ maskp, float* __restrict__ out, int N)
{
    __shared__ float sf[1024];
    __shared__ int   si[1024];
    const int t = threadIdx.x;
    const bool as_int = (g_mask_int != 0);
    float s = 0.0f;
    int   c = 0;
    for (int idx = t; idx < N; idx += 1024) {
        s += g_row[idx];
        c += mask_at(maskp, idx, as_int) ? 1 : 0;
    }
    sf[t] = s; si[t] = c;
    __syncthreads();
    for (int off = 512; off > 0; off >>= 1) {
        if (t < off) { sf[t] += sf[t + off]; si[t] += si[t + off]; }
        __syncthreads();
    }
    if (t == 0) out[0] = sf[0] / (float)si[0];
}

extern "C" void kernel_launch(void* const* d_in, const int* in_sizes, int n_in,
                              void* d_out, int out_size, void* d_ws, size_t ws_size,
                              hipStream_t stream) {
    const float* inp  = (const float*)d_in[0];
    const float* tgt  = (const float*)d_in[1];
    const float* q    = (const float*)d_in[2];
    const int*   tids = (const int*)d_in[3];
    const int*   uids = (const int*)d_in[4];
    const void*  mask = d_in[5];
    const int N = in_sizes[2];  // q_probas element count

    build_buckets<<<1, N_USERS, 0, stream>>>(mask, uids, N);
    row_kernel<<<FB_BLOCKS + REG_BLOCKS, 1024, 0, stream>>>(
        inp, tgt, q, tids, uids, mask, N);
    finalize<<<1, 1024, 0, stream>>>(mask, (float*)d_out, N);
}

// Round 5
// 51.030 us; speedup vs baseline: 1.3021x; 1.3021x over previous
//
#include <hip/hip_runtime.h>
#include <math.h>

#define N_MAX 8192
#define N_USERS 1024
#define D 64
#define NCH 8            // fallback chunks (1024 negs each; 8*1024 = N_MAX)
#define RG_SLOTS 8       // fallback row-group slots (16 rows each)
#define FB_BLOCKS (NCH * RG_SLOTS)   // 64 fallback blocks, lowest ids
#define REG_BLOCKS 512   // 16 waves -> 16 rows per block

// Persistent device scratch (rewritten deterministically every launch).
__device__ int   g_mask_int;            // 1 if mask buffer is int32, 0 if bytes
__device__ int   g_off[N_USERS + 1];    // exclusive prefix offsets per user
__device__ int   g_list[N_MAX];         // negative column idx, bucketed by user
__device__ int   g_nfb;                 // # fallback rows
__device__ int   g_fb[N_MAX];           // fallback row ids
__device__ float g_pos[N_MAX];          // pos_sim for fallback rows
__device__ float g_ps[N_MAX][NCH];      // fallback partial sums (by fb-list pos)
__device__ int   g_pn[N_MAX][NCH];      // fallback partial counts
__device__ float g_row[N_MAX];          // per-row loss (0 for unmasked rows)

__device__ __forceinline__ bool mask_at(const void* m, int k, bool as_int) {
    return as_int ? (((const int*)m)[k] != 0)
                  : (((const unsigned char*)m)[k] != 0);
}

// ---------------------------------------------------------------------------
// Kernel 1: detect mask dtype; bucket negative columns by user id; emit
// masked rows with empty buckets. Single block of 1024 threads.
// ---------------------------------------------------------------------------
__global__ __launch_bounds__(N_USERS) void build_buckets(
    const void* __restrict__ maskp,
    const int* __restrict__ uid, int N)
{
    const int t    = threadIdx.x;
    const int lane = t & 63;
    const int w    = t >> 6;
    __shared__ int cntA[N_USERS];
    __shared__ int cur[N_USERS];
    __shared__ int wsum[16];
    __shared__ int s_or;

    if (t == 0) { s_or = 0; g_nfb = 0; }
    cntA[t] = 0;
    __syncthreads();

    // mask dtype detection: int32 0/1 has zero bytes at k%4!=0
    {
        const unsigned char* mb = (const unsigned char*)maskp;
        int z = 0;
        for (int k = t; k < N; k += N_USERS)
            if (k & 3) z |= mb[k];
        if (z) atomicOr(&s_or, 1);
    }
    __syncthreads();
    const bool as_int = (s_or == 0);
    if (t == 0) g_mask_int = as_int ? 1 : 0;

    for (int k = t; k < N; k += N_USERS)
        if (!mask_at(maskp, k, as_int)) atomicAdd(&cntA[uid[k]], 1);
    __syncthreads();

    // exclusive scan over 1024 counts: wave shfl-scan + wave-sum scan
    const int own = cntA[t];
    int inc = own;
    #pragma unroll
    for (int off = 1; off < 64; off <<= 1) {
        int u = __shfl_up(inc, off, 64);
        if (lane >= off) inc += u;
    }
    if (lane == 63) wsum[w] = inc;
    __syncthreads();
    if (w == 0) {
        int s = (lane < 16) ? wsum[lane] : 0;
        #pragma unroll
        for (int off = 1; off < 16; off <<= 1) {
            int u = __shfl_up(s, off, 64);
            if (lane >= off) s += u;
        }
        if (lane < 16) wsum[lane] = s;
    }
    __syncthreads();
    const int base = (w > 0) ? wsum[w - 1] : 0;
    const int excl = base + inc - own;
    g_off[t] = excl;
    if (t == N_USERS - 1) g_off[N_USERS] = base + inc;
    cur[t] = excl;
    __syncthreads();

    for (int k = t; k < N; k += N_USERS)
        if (!mask_at(maskp, k, as_int)) {
            int p = atomicAdd(&cur[uid[k]], 1);
            g_list[p] = k;
        }

    for (int i = t; i < N; i += N_USERS)
        if (mask_at(maskp, i, as_int) && cntA[uid[i]] == 0) {
            int p = atomicAdd(&g_nfb, 1);
            g_fb[p] = i;
        }
}

// ---------------------------------------------------------------------------
// Kernel 2 (fused).
//  blocks [0, FB_BLOCKS): fallback partials. Block = (chunk c, row-group rg):
//    thread-per-negative (ONE gather chain deep), 16 fb input rows staged in
//    LDS, 16 dots per thread from registers -> two-stage reduce -> g_ps/g_pn.
//  blocks [FB_BLOCKS, +REG_BLOCKS): one wave per regular row (bucket scan,
//    16-lane coalesced row reads).
// ---------------------------------------------------------------------------
__global__ __launch_bounds__(1024) void row_kernel(
    const float* __restrict__ inp, const float* __restrict__ tgt,
    const float* __restrict__ q,   const int* __restrict__ tids,
    const int* __restrict__ uid,   const void* __restrict__ maskp,
    int N)
{
    const int t    = threadIdx.x;
    const int lane = t & 63;
    const int w    = t >> 6;
    const int bid  = blockIdx.x;
    const bool as_int = (g_mask_int != 0);

    if (bid >= FB_BLOCKS) {
        // ---------------- regular rows: one wave each ----------------------
        const int i = (bid - FB_BLOCKS) * 16 + w;
        if (i >= N) return;
        if (!mask_at(maskp, i, as_int)) { if (lane == 0) g_row[i] = 0.0f; return; }

        const float a = inp[i * D + lane];
        float p = a * tgt[i * D + lane];
        #pragma unroll
        for (int o = 32; o > 0; o >>= 1) p += __shfl_xor(p, o, 64);

        const int u = uid[i];
        const int start = g_off[u], end = g_off[u + 1];
        if (end == start) {                  // fallback machinery owns negs
            if (lane == 0) g_pos[i] = p;
            return;
        }

        const int sub = lane & 15;           // float4 slot within a row
        const int kg  = lane >> 4;           // 4 k-groups per wave
        float4 a4;
        a4.x = __shfl(a, (sub << 2) + 0, 64);
        a4.y = __shfl(a, (sub << 2) + 1, 64);
        a4.z = __shfl(a, (sub << 2) + 2, 64);
        a4.w = __shfl(a, (sub << 2) + 3, 64);

        const int my_tid = tids[i];
        float s = 0.0f;
        int   n = 0;
        for (int j = start + kg; j < end; j += 4) {
            const int k = g_list[j];
            const float4 t4 = *(const float4*)(tgt + k * D + (sub << 2));
            float dot = a4.x * t4.x + a4.y * t4.y + a4.z * t4.z + a4.w * t4.w;
            #pragma unroll
            for (int o = 8; o > 0; o >>= 1) dot += __shfl_xor(dot, o, 16);
            if (sub == 0 && tids[k] != my_tid) { s += expf(dot) / q[k]; n++; }
        }
        #pragma unroll
        for (int o = 32; o > 0; o >>= 1) {
            s += __shfl_xor(s, o, 64);
            n += __shfl_xor(n, o, 64);
        }
        if (lane == 0) {
            const float qi      = q[i];
            const float neg_sum = (1.0f - qi) * s / fmaxf((float)n, 1.0f);
            g_row[i] = log1pf(neg_sum * expf(-p));
        }
    } else {
        // ---------------- fallback partials --------------------------------
        const int c   = bid & (NCH - 1);     // neg chunk
        const int rg0 = bid >> 3;            // row-group slot
        const int nfb = g_nfb;
        const int ntot = g_off[N_USERS];
        __shared__ __align__(16) float in_fb[16][D];
        __shared__ int   s_tid[16];
        __shared__ float ws_s[16][16];       // [wave][row]
        __shared__ int   ws_n[16][16];

        for (int rg = rg0; rg * 16 < nfb; rg += RG_SLOTS) {
            const int nr = min(16, nfb - rg * 16);
            {   // stage 16 fb input rows + their tids
                const int r = t >> 6, d = t & 63;
                if (r < nr) in_fb[r][d] = inp[g_fb[rg * 16 + r] * D + d];
                if (t < nr) s_tid[t] = tids[g_fb[rg * 16 + t]];
            }
            __syncthreads();

            const int k_idx = c * 1024 + t;
            float ps[16];
            int   pn[16];
            #pragma unroll
            for (int r = 0; r < 16; ++r) { ps[r] = 0.0f; pn[r] = 0; }

            if (k_idx < ntot) {
                const int   k  = g_list[k_idx];
                const int   tk = tids[k];
                const float rq = 1.0f / q[k];
                float4 treg[D / 4];
                #pragma unroll
                for (int d4 = 0; d4 < D / 4; ++d4)
                    treg[d4] = ((const float4*)(tgt + k * D))[d4];
                #pragma unroll
                for (int r = 0; r < 16; ++r) {   // full unroll, static idx
                    const float4* ar = (const float4*)in_fb[r];
                    float dot = 0.0f;
                    #pragma unroll
                    for (int d4 = 0; d4 < D / 4; ++d4) {
                        const float4 a4 = ar[d4];
                        const float4 t4 = treg[d4];
                        dot += a4.x * t4.x + a4.y * t4.y + a4.z * t4.z + a4.w * t4.w;
                    }
                    if (tk != s_tid[r]) { ps[r] = expf(dot) * rq; pn[r] = 1; }
                }
            }

            // two-stage reduce: wave shuffle -> LDS -> wave 0
            #pragma unroll
            for (int r = 0; r < 16; ++r) {
                float s = ps[r]; int n = pn[r];
                #pragma unroll
                for (int o = 32; o > 0; o >>= 1) {
                    s += __shfl_xor(s, o, 64);
                    n += __shfl_xor(n, o, 64);
                }
                if (lane == 0) { ws_s[w][r] = s; ws_n[w][r] = n; }
            }
            __syncthreads();
            if (w == 0 && lane < nr) {
                float S = 0.0f; int Nn = 0;
                #pragma unroll
                for (int x = 0; x < 16; ++x) { S += ws_s[x][lane]; Nn += ws_n[x][lane]; }
                g_ps[rg * 16 + lane][c] = S;
                g_pn[rg * 16 + lane][c] = Nn;
            }
            __syncthreads();                 // protect LDS reuse next rg
        }
    }
}

// ---------------------------------------------------------------------------
// Kernel 3: combine fallback partials (fixed chunk order -> deterministic),
// then fixed-order global reduction -> scalar loss.
// ---------------------------------------------------------------------------
__global__ __launch_bounds__(1024) void finalize(
    const void* __restrict__ maskp, const float* __restrict__ q,
    float* __restrict__ out, int N)
{
    __shared__ float sf[1024];
    __shared__ int   si[1024];
    const int t = threadIdx.x;
    const bool as_int = (g_mask_int != 0);

    const int nfb = g_nfb;
    for (int r = t; r < nfb; r += 1024) {
        float S = 0.0f; int Nn = 0;
        #pragma unroll
        for (int c = 0; c < NCH; ++c) { S += g_ps[r][c]; Nn += g_pn[r][c]; }
        const int i = g_fb[r];
        const float qi      = q[i];
        const float neg_sum = (1.0f - qi) * S / fmaxf((float)Nn, 1.0f);
        g_row[i] = log1pf(neg_sum * expf(-g_pos[i]));
    }
    __syncthreads();

    float s = 0.0f;
    int   c = 0;
    for (int idx = t; idx < N; idx += 1024) {
        s += g_row[idx];
        c += mask_at(maskp, idx, as_int) ? 1 : 0;
    }
    sf[t] = s; si[t] = c;
    __syncthreads();
    for (int off = 512; off > 0; off >>= 1) {
        if (t < off) { sf[t] += sf[t + off]; si[t] += si[t + off]; }
        __syncthreads();
    }
    if (t == 0) out[0] = sf[0] / (float)si[0];
}

extern "C" void kernel_launch(void* const* d_in, const int* in_sizes, int n_in,
                              void* d_out, int out_size, void* d_ws, size_t ws_size,
                              hipStream_t stream) {
    const float* inp  = (const float*)d_in[0];
    const float* tgt  = (const float*)d_in[1];
    const float* q    = (const float*)d_in[2];
    const int*   tids = (const int*)d_in[3];
    const int*   uids = (const int*)d_in[4];
    const void*  mask = d_in[5];
    const int N = in_sizes[2];  // q_probas element count

    build_buckets<<<1, N_USERS, 0, stream>>>(mask, uids, N);
    row_kernel<<<FB_BLOCKS + REG_BLOCKS, 1024, 0, stream>>>(
        inp, tgt, q, tids, uids, mask, N);
    finalize<<<1, 1024, 0, stream>>>(mask, q, (float*)d_out, N);
}

// Round 6
// 35.523 us; speedup vs baseline: 1.8705x; 1.4365x over previous
//
#include <hip/hip_runtime.h>
#include <math.h>

#define N_MAX 8192
#define N_USERS 1024
#define D 64
#define NCH 32           // fallback chunks of 256 negatives
#define CHSZ 256
#define RG_SLOTS 8       // fallback row-group slots (16 rows each)
#define FB_BLOCKS (NCH * RG_SLOTS)   // 256 fallback blocks, lowest ids

// Persistent device scratch (rewritten deterministically every launch).
__device__ int   g_nfb;               // # fallback rows
__device__ int   g_ntot;              // total negatives
__device__ int4  g_plan[N_MAX];       // {code 0=unmasked 1=regular 2=fallback, start, end, tid_i}
__device__ int4  g_klist[N_MAX];      // {k, tid_k, bits(1/q_k), 0}
__device__ int   g_fb[N_MAX];         // fallback row ids
__device__ float g_pos[N_MAX];        // pos_sim for fallback rows
__device__ float g_ps[N_MAX][NCH];    // fallback partial sums
__device__ int   g_pn[N_MAX][NCH];    // fallback partial counts
__device__ float g_row[N_MAX];        // per-row loss (0 for unmasked rows)

__device__ __forceinline__ bool mask_at(const void* m, int k, bool as_int) {
    return as_int ? (((const int*)m)[k] != 0)
                  : (((const unsigned char*)m)[k] != 0);
}

// ---------------------------------------------------------------------------
// Kernel 1: one 1024-thread block. Detect mask dtype (single-byte probe),
// count negatives per user, shfl-scan, then ONE merged pass that scatters the
// packed klist AND writes the per-row plan AND collects fallback rows.
// ---------------------------------------------------------------------------
__global__ __launch_bounds__(1024) void build_buckets(
    const float* __restrict__ q,   const int* __restrict__ tids,
    const int* __restrict__ uid,   const void* __restrict__ maskp, int N)
{
    const int t    = threadIdx.x;
    const int lane = t & 63;
    const int w    = t >> 6;
    __shared__ int cntA[N_USERS];
    __shared__ int offs[N_USERS + 1];
    __shared__ int cur[N_USERS];
    __shared__ int wsum[16];
    __shared__ int s_or, s_nfb;

    if (t == 0) { s_or = 0; s_nfb = 0; }
    cntA[t] = 0;
    __syncthreads();

    // mask dtype probe: int32 0/1 has zero bytes wherever k%4!=0.
    // 768 one-byte probes; P(all zero | byte-mask) = 2^-384.
    if (t < N && (t & 3))
        if (((const unsigned char*)maskp)[t]) atomicOr(&s_or, 1);
    __syncthreads();
    const bool as_int = (s_or == 0);

    // count negatives per user
    for (int k = t; k < N; k += N_USERS)
        if (!mask_at(maskp, k, as_int)) atomicAdd(&cntA[uid[k]], 1);
    __syncthreads();

    // exclusive scan over 1024 counts: wave shfl-scan + wave-sum scan
    const int own = cntA[t];
    int inc = own;
    #pragma unroll
    for (int off = 1; off < 64; off <<= 1) {
        int u = __shfl_up(inc, off, 64);
        if (lane >= off) inc += u;
    }
    if (lane == 63) wsum[w] = inc;
    __syncthreads();
    if (w == 0) {
        int s = (lane < 16) ? wsum[lane] : 0;
        #pragma unroll
        for (int off = 1; off < 16; off <<= 1) {
            int u = __shfl_up(s, off, 64);
            if (lane >= off) s += u;
        }
        if (lane < 16) wsum[lane] = s;
    }
    __syncthreads();
    const int base = (w > 0) ? wsum[w - 1] : 0;
    const int excl = base + inc - own;
    offs[t] = excl;
    cur[t]  = excl;
    if (t == N_USERS - 1) offs[N_USERS] = base + inc;
    __syncthreads();

    // merged pass: scatter klist / write plan / collect fallback rows
    for (int idx = t; idx < N; idx += N_USERS) {
        const bool m  = mask_at(maskp, idx, as_int);
        const int  u  = uid[idx];
        const int  ti = tids[idx];
        int4 pl;
        if (m) {
            const int cnt = cntA[u];
            int code = 1;
            if (cnt == 0) { int p = atomicAdd(&s_nfb, 1); g_fb[p] = idx; code = 2; }
            pl = make_int4(code, offs[u], offs[u] + cnt, ti);
        } else {
            const float rq = 1.0f / q[idx];
            int p = atomicAdd(&cur[u], 1);
            g_klist[p] = make_int4(idx, ti, __float_as_int(rq), 0);
            pl = make_int4(0, 0, 0, ti);
        }
        g_plan[idx] = pl;
    }
    __syncthreads();
    if (t == 0) { g_nfb = s_nfb; g_ntot = offs[N_USERS]; }
}

// ---------------------------------------------------------------------------
// Kernel 2 (fused), 256-thread blocks.
//  blocks [0, FB_BLOCKS): fallback partials. Block = (chunk c of 256 negs,
//    row-group rg of 16 fb rows); thread-per-negative, ONE gather chain deep,
//    16 dots from LDS-broadcast rows -> shfl reduce -> g_ps/g_pn.
//  blocks [FB_BLOCKS, ...): 4 waves/block, one row per wave. All independent
//    loads (plan, inp row, tgt row, q, a4) issued at wave start; chain is
//    plan -> klist -> tgt[k] only.
// ---------------------------------------------------------------------------
__global__ __launch_bounds__(256) void row_kernel(
    const float* __restrict__ inp, const float* __restrict__ tgt,
    const float* __restrict__ q,   int N)
{
    const int t    = threadIdx.x;
    const int lane = t & 63;
    const int w    = t >> 6;
    const int bid  = blockIdx.x;

    if (bid >= FB_BLOCKS) {
        // ---------------- regular rows: one wave each ----------------------
        const int i = (bid - FB_BLOCKS) * 4 + w;
        if (i >= N) return;
        const int sub = lane & 15;           // float4 slot within a row
        const int kg  = lane >> 4;           // 4 k-groups per wave

        // all independent loads up front
        const float  a  = inp[i * D + lane];
        const float  b  = tgt[i * D + lane];
        const float4 a4 = ((const float4*)(inp + i * D))[sub];
        const float  qi = q[i];
        const int4   pl = g_plan[i];

        float p = a * b;
        #pragma unroll
        for (int o = 32; o > 0; o >>= 1) p += __shfl_xor(p, o, 64);

        if (pl.x == 0) { if (lane == 0) g_row[i] = 0.0f; return; }
        if (pl.x == 2) { if (lane == 0) g_pos[i] = p;    return; }

        float s = 0.0f;
        int   n = 0;
        for (int j = pl.y + kg; j < pl.z; j += 4) {
            const int4 kk = g_klist[j];                    // broadcast in group
            const float4 t4 = *(const float4*)(tgt + kk.x * D + (sub << 2));
            float dot = a4.x * t4.x + a4.y * t4.y + a4.z * t4.z + a4.w * t4.w;
            #pragma unroll
            for (int o = 8; o > 0; o >>= 1) dot += __shfl_xor(dot, o, 16);
            if (sub == 0 && kk.y != pl.w) { s += expf(dot) * __int_as_float(kk.z); n++; }
        }
        s += __shfl_xor(s, 16, 64); s += __shfl_xor(s, 32, 64);
        n += __shfl_xor(n, 16, 64); n += __shfl_xor(n, 32, 64);
        if (lane == 0) {
            const float neg_sum = (1.0f - qi) * s / fmaxf((float)n, 1.0f);
            g_row[i] = log1pf(neg_sum * expf(-p));
        }
    } else {
        // ---------------- fallback partials --------------------------------
        const int c   = bid & (NCH - 1);     // neg chunk
        const int rg0 = bid >> 5;            // row-group slot
        const int nfb = g_nfb, ntot = g_ntot;
        __shared__ __align__(16) float in_fb[16][D];
        __shared__ int   s_tid[16];
        __shared__ float ws_s[4][16];
        __shared__ int   ws_n[4][16];

        for (int rg = rg0; rg * 16 < nfb; rg += RG_SLOTS) {
            const int nr = min(16, nfb - rg * 16);
            for (int e = t; e < (nr << 6); e += 256)
                in_fb[e >> 6][e & 63] = inp[g_fb[rg * 16 + (e >> 6)] * D + (e & 63)];
            if (t < nr) s_tid[t] = g_plan[g_fb[rg * 16 + t]].w;
            __syncthreads();

            const int k_idx = c * CHSZ + t;  // one negative per thread
            float dot[16];
            #pragma unroll
            for (int r = 0; r < 16; ++r) dot[r] = 0.0f;
            int kk_tid = 0; float rq = 0.0f;
            const bool act = (k_idx < ntot);
            if (act) {
                const int4 kk = g_klist[k_idx];
                kk_tid = kk.y; rq = __int_as_float(kk.z);
                const float4* trow = (const float4*)(tgt + kk.x * D);
                #pragma unroll
                for (int d4 = 0; d4 < D / 4; ++d4) {
                    const float4 t4 = trow[d4];
                    #pragma unroll
                    for (int r = 0; r < 16; ++r) {
                        const float4 af = ((const float4*)in_fb[r])[d4];
                        dot[r] += af.x * t4.x + af.y * t4.y + af.z * t4.z + af.w * t4.w;
                    }
                }
            }
            #pragma unroll
            for (int r = 0; r < 16; ++r) {
                const bool hit = act && (kk_tid != s_tid[r]);
                float s = hit ? expf(dot[r]) * rq : 0.0f;
                int   n = hit ? 1 : 0;
                #pragma unroll
                for (int o = 32; o > 0; o >>= 1) {
                    s += __shfl_xor(s, o, 64);
                    n += __shfl_xor(n, o, 64);
                }
                if (lane == 0) { ws_s[w][r] = s; ws_n[w][r] = n; }
            }
            __syncthreads();
            if (w == 0 && lane < nr) {
                const float S  = ws_s[0][lane] + ws_s[1][lane] + ws_s[2][lane] + ws_s[3][lane];
                const int   Nn = ws_n[0][lane] + ws_n[1][lane] + ws_n[2][lane] + ws_n[3][lane];
                g_ps[rg * 16 + lane][c] = S;
                g_pn[rg * 16 + lane][c] = Nn;
            }
            __syncthreads();                 // protect LDS reuse next rg
        }
    }
}

// ---------------------------------------------------------------------------
// Kernel 3: combine fallback partials (fixed chunk order), then fixed-order
// global reduction -> scalar loss. Mask count taken from plan codes.
// ---------------------------------------------------------------------------
__global__ __launch_bounds__(1024) void finalize(
    const float* __restrict__ q, float* __restrict__ out, int N)
{
    __shared__ float sf[1024];
    __shared__ int   si[1024];
    const int t = threadIdx.x;

    const int nfb = g_nfb;
    for (int r = t; r < nfb; r += 1024) {
        float S = 0.0f; int Nn = 0;
        #pragma unroll
        for (int c = 0; c < NCH; ++c) { S += g_ps[r][c]; Nn += g_pn[r][c]; }
        const int i = g_fb[r];
        const float neg_sum = (1.0f - q[i]) * S / fmaxf((float)Nn, 1.0f);
        g_row[i] = log1pf(neg_sum * expf(-g_pos[i]));
    }
    __syncthreads();

    float s = 0.0f;
    int   c = 0;
    for (int idx = t; idx < N; idx += 1024) {
        s += g_row[idx];
        c += (g_plan[idx].x != 0) ? 1 : 0;
    }
    sf[t] = s; si[t] = c;
    __syncthreads();
    for (int off = 512; off > 0; off >>= 1) {
        if (t < off) { sf[t] += sf[t + off]; si[t] += si[t + off]; }
        __syncthreads();
    }
    if (t == 0) out[0] = sf[0] / (float)si[0];
}

extern "C" void kernel_launch(void* const* d_in, const int* in_sizes, int n_in,
                              void* d_out, int out_size, void* d_ws, size_t ws_size,
                              hipStream_t stream) {
    const float* inp  = (const float*)d_in[0];
    const float* tgt  = (const float*)d_in[1];
    const float* q    = (const float*)d_in[2];
    const int*   tids = (const int*)d_in[3];
    const int*   uids = (const int*)d_in[4];
    const void*  mask = d_in[5];
    const int N = in_sizes[2];  // q_probas element count

    build_buckets<<<1, 1024, 0, stream>>>(q, tids, uids, mask, N);
    row_kernel<<<FB_BLOCKS + (N + 3) / 4, 256, 0, stream>>>(inp, tgt, q, N);
    finalize<<<1, 1024, 0, stream>>>(q, (float*)d_out, N);
}